// Round 10
// baseline (175.897 us; speedup 1.0000x reference)
//
#include <hip/hip_runtime.h>
#include <math.h>

// WfcNN: B=262144.
//   h1 = tanh(x @ W0 + b0)            (B,128)
//   h2 = tanh(h1 @ W1 + b1)           (B,64)
//   g  = tanh(h2 . Wa[eid] + ba[eid]) (B,32)
//   psi= g . Wb[eid] + bb[eid]        (B,2) ; out = psi / sqrt(|psi|^2+1e-6)
//
// Round 10:
//  - Layer-2 A-fragments computed DIRECTLY in registers (lane computes
//    h[sample=l16-of-tile][k=qd*8+j] from gathered x + float4 W0 rows).
//    Kills the whole layer-2 LDS round trip: 8 barriers, 128 ds ops,
//    pack/unpack for A. Bit-identical MFMA inputs -> absmax unchanged.
//  - Memset node removed: hist writes per-block counts; scatter derives
//    scan + per-block bases from the count table; block 0 publishes etot.
//  - h2-restage + g-stage + expert-B unchanged (validated R5-R9).
//  - Cooperative fusion is OFF-LIMITS (R8: hipLaunchCooperativeKernel fails
//    in this harness).

#define THREADS 256
#define NE 30
#define HB 128
#define MAXBLK 1056
#define SA 259            // u32 row stride for [d][sample] h2 staging
#define SG 36             // f32 row stride for [sample][h] g staging

typedef short bf16x8 __attribute__((ext_vector_type(8)));
typedef float f32x4 __attribute__((ext_vector_type(4)));

__device__ __forceinline__ int expert_id(int nn, int ll, int mm) {
    return ((nn - 1) * nn * (2 * nn - 1)) / 6 + ll * ll + ll + mm;
}

// tanh(v) = 1 - 2/(exp2(2*log2e*v)+1); saturates correctly, no clamp.
__device__ __forceinline__ float fast_tanh(float v) {
    float e = __builtin_exp2f(v * 2.885390082f);
    return fmaf(-2.0f, __builtin_amdgcn_rcpf(e + 1.0f), 1.0f);
}

__device__ __forceinline__ unsigned int f2b(float f) {   // f32 -> bf16 RNE
    unsigned int u = __float_as_uint(f);
    return (u + 0x7fffu + ((u >> 16) & 1u)) >> 16;
}
__device__ __forceinline__ float b2f(unsigned int b) {
    return __uint_as_float(b << 16);
}
// runtime split: RNE hi, truncated lo; packed (lo16<<16)|hi16
__device__ __forceinline__ unsigned int packsplit(float v) {
    const unsigned int hb = f2b(v);
    const float lo = v - b2f(hb);
    return (__float_as_uint(lo) & 0xffff0000u) | hb;
}

union U8 { unsigned int u[4]; bf16x8 v; };
// packed words -> hi-plane / lo-plane bf16x8
__device__ __forceinline__ void unpack8(const unsigned int* w, bf16x8& hi, bf16x8& lo) {
    U8 H, L;
#pragma unroll
    for (int i = 0; i < 4; ++i) {
        H.u[i] = __builtin_amdgcn_perm(w[2 * i + 1], w[2 * i], 0x05040100u);
        L.u[i] = __builtin_amdgcn_perm(w[2 * i + 1], w[2 * i], 0x07060302u);
    }
    hi = H.v; lo = L.v;
}

union V8 { unsigned short s[8]; bf16x8 v; };

// ---- K1: per-block hist (no atomics on globals) + eid cache + weight split ----
__global__ void hist_pack_kernel(const int* __restrict__ nq, const int* __restrict__ lq,
                                 const int* __restrict__ mq,
                                 int* __restrict__ eids, int* __restrict__ bcnt,
                                 const float* __restrict__ W1,
                                 unsigned short* __restrict__ W1fh, unsigned short* __restrict__ W1fl,
                                 const float* __restrict__ Wa,
                                 unsigned short* __restrict__ Wafh, unsigned short* __restrict__ Wafl,
                                 int B) {
    const int tid = threadIdx.x;
    const int bx = blockIdx.x;
    if (bx < HB) {
        __shared__ int h[NE];
        if (tid < NE) h[tid] = 0;
        __syncthreads();
        const int per = B / HB, base = bx * per;
        for (int i = tid; i < per; i += blockDim.x) {
            const int e = expert_id(nq[base + i], lq[base + i], mq[base + i]);
            eids[base + i] = e;
            atomicAdd(&h[e], 1);
        }
        __syncthreads();
        if (tid < NE) bcnt[bx * NE + tid] = h[tid];
    } else if (bx == HB) {
        // W1 (128,64) -> hi/lo planes in B-frag order (rec=((c*4+nt)*4+qd)*16+l16)
        for (int i = tid; i < 8192; i += blockDim.x) {
            const int j = i & 7, s = (i >> 3) & 15, q = (i >> 7) & 3;
            const int nt = (i >> 9) & 3, c = i >> 11;
            const int k = c * 32 + q * 8 + j, n = nt * 16 + s;
            const float w = W1[k * 64 + n];
            const unsigned int hb = f2b(w);
            W1fh[i] = (unsigned short)hb;
            W1fl[i] = (unsigned short)f2b(w - b2f(hb));
        }
    } else {
        // Wa[e] (64,32) -> hi/lo planes (rec=((c2*2+nt2)*4+qd)*16+l16)
        const int e = bx - HB - 1;
        for (int i = tid; i < 2048; i += blockDim.x) {
            const int j = i & 7, s = (i >> 3) & 15, q = (i >> 7) & 3;
            const int nt2 = (i >> 9) & 1, c2 = (i >> 10) & 1;
            const int d = c2 * 32 + q * 8 + j, hh = nt2 * 16 + s;
            const float w = Wa[e * 2048 + d * 32 + hh];
            const unsigned int hb = f2b(w);
            Wafh[e * 2048 + i] = (unsigned short)hb;
            Wafl[e * 2048 + i] = (unsigned short)f2b(w - b2f(hb));
        }
    }
}

// ---- K2: scatter; derives scan + own bases from count table; publishes etot ----
__global__ void scatter_kernel(const int* __restrict__ eids, const int* __restrict__ bcnt,
                               int* __restrict__ etot, int* __restrict__ perm, int B) {
    __shared__ int sh[HB * NE];
    __shared__ int esrt[NE], bb[NE], lcnt[NE], tot[NE];
    const int tid = threadIdx.x;
    for (int i = tid; i < HB * NE; i += blockDim.x) sh[i] = bcnt[i];
    if (tid < NE) lcnt[tid] = 0;
    __syncthreads();
    if (tid < NE) {
        int pre = 0, t = 0;
        for (int b = 0; b < HB; ++b) {
            const int v = sh[b * NE + tid];
            if (b < (int)blockIdx.x) pre += v;
            t += v;
        }
        tot[tid] = t;
        bb[tid] = pre;
        if (blockIdx.x == 0) etot[tid] = t;     // publish for wfc
    }
    __syncthreads();
    if (tid == 0) {
        int es = 0;
        for (int e = 0; e < NE; ++e) { esrt[e] = es; es += tot[e]; }
    }
    __syncthreads();
    const int per = B / gridDim.x;
    const int blk = blockIdx.x * per;
    for (int i = tid; i < per; i += blockDim.x) {
        const int idx = blk + i;
        const int e = eids[idx];
        const int r = atomicAdd(&lcnt[e], 1);
        perm[esrt[e] + bb[e] + r] = idx;
    }
}

// ---- K3: fused MLP; layer2 + expert-A on MFMA (3-pass split-bf16) ----
__global__ __launch_bounds__(THREADS, 3) void wfc_kernel(
    const float* __restrict__ x, const int* __restrict__ perm,
    const int* __restrict__ etot,
    const float* __restrict__ W0, const float* __restrict__ b0,
    const bf16x8* __restrict__ W1fh, const bf16x8* __restrict__ W1fl,
    const float* __restrict__ b1,
    const bf16x8* __restrict__ Wafh, const bf16x8* __restrict__ Wafl,
    const float* __restrict__ ba,
    const float* __restrict__ Wb, const float* __restrict__ bb,
    float* __restrict__ out)
{
    __shared__ unsigned int sbuf[9216];      // 36,864 B (h2 restage / g stage)

    // derive (eid, start, cnt) from etot: uniform scalar 30-iter scan
    int eid = -1, start = 0, cnt = 0;
    {
        int cum = 0, es = 0;
#pragma unroll 1
        for (int e = 0; e < NE; ++e) {
            const int t = etot[e];
            const int nb = (t + THREADS - 1) >> 8;
            if ((int)blockIdx.x < cum + nb) {
                const int seg = blockIdx.x - cum;
                eid = e; start = es + seg * THREADS; cnt = min(THREADS, t - seg * THREADS);
                break;
            }
            cum += nb; es += t;
        }
    }
    if (eid < 0) return;
    eid = __builtin_amdgcn_readfirstlane(eid);

    const int tid = threadIdx.x;
    const bool valid = tid < cnt;
    const int idx = perm[start + (valid ? tid : 0)];

    const int lane = tid & 63;
    const int wv   = tid >> 6;
    const int qd   = lane >> 4;
    const int l16  = lane & 15;

    // x gather for the 4 sample rows (one per m-tile) this lane's A-frags need
    float xa[4], xb[4], xc[4];
#pragma unroll
    for (int mt = 0; mt < 4; ++mt) {
        const int mrow = wv * 64 + mt * 16 + l16;
        const int p = perm[start + (mrow < cnt ? mrow : 0)];
        xa[mt] = x[p * 3 + 0];
        xb[mt] = x[p * 3 + 1];
        xc[mt] = x[p * 3 + 2];
    }

    // ---- layer 2 accumulators, init b1 (C layout: col = l16) ----
    f32x4 acc[4][4];
#pragma unroll
    for (int nt = 0; nt < 4; ++nt) {
        const float bv = b1[nt * 16 + l16];
#pragma unroll
        for (int mt = 0; mt < 4; ++mt) {
            f32x4 c; c[0] = bv; c[1] = bv; c[2] = bv; c[3] = bv;
            acc[mt][nt] = c;
        }
    }

    // ---- layer-2 GEMM: 4 K-chunks of 32; A-frags computed in registers ----
#pragma unroll 1
    for (int c = 0; c < 4; ++c) {
        const int kb = c * 32 + qd * 8;           // this quad's 8 k's
        float wr0[8], wr1[8], wr2[8], wr3[8];
        *(float4*)&wr0[0] = *(const float4*)(W0 + kb);
        *(float4*)&wr0[4] = *(const float4*)(W0 + kb + 4);
        *(float4*)&wr1[0] = *(const float4*)(W0 + 128 + kb);
        *(float4*)&wr1[4] = *(const float4*)(W0 + 128 + kb + 4);
        *(float4*)&wr2[0] = *(const float4*)(W0 + 256 + kb);
        *(float4*)&wr2[4] = *(const float4*)(W0 + 256 + kb + 4);
        *(float4*)&wr3[0] = *(const float4*)(b0 + kb);
        *(float4*)&wr3[4] = *(const float4*)(b0 + kb + 4);

        // build all 4 A-frag pairs first (lets wr* die before B-frags load)
        bf16x8 Ahi[4], Alo[4];
#pragma unroll
        for (int mt = 0; mt < 4; ++mt) {
            V8 Ah, Al;
#pragma unroll
            for (int j = 0; j < 8; ++j) {
                const float pre = fmaf(xa[mt], wr0[j],
                                  fmaf(xb[mt], wr1[j],
                                  fmaf(xc[mt], wr2[j], wr3[j])));
                const float h = fast_tanh(pre);
                const unsigned int hb = f2b(h);
                Ah.s[j] = (unsigned short)hb;
                Al.s[j] = (unsigned short)(__float_as_uint(h - b2f(hb)) >> 16);
            }
            Ahi[mt] = Ah.v;
            Alo[mt] = Al.v;
        }

        bf16x8 Bhi[4], Blo[4];
#pragma unroll
        for (int nt = 0; nt < 4; ++nt) {
            const int rec = (c * 4 + nt) * 64 + qd * 16 + l16;
            Bhi[nt] = W1fh[rec];
            Blo[nt] = W1fl[rec];
        }
#pragma unroll
        for (int mt = 0; mt < 4; ++mt) {
#pragma unroll
            for (int nt = 0; nt < 4; ++nt) {
                acc[mt][nt] = __builtin_amdgcn_mfma_f32_16x16x32_bf16(Ahi[mt], Bhi[nt], acc[mt][nt], 0, 0, 0);
                acc[mt][nt] = __builtin_amdgcn_mfma_f32_16x16x32_bf16(Ahi[mt], Blo[nt], acc[mt][nt], 0, 0, 0);
                acc[mt][nt] = __builtin_amdgcn_mfma_f32_16x16x32_bf16(Alo[mt], Bhi[nt], acc[mt][nt], 0, 0, 0);
            }
        }
    }

    // ---- expert-A accumulators, init ba ----
    f32x4 acc2[4][2];
#pragma unroll
    for (int nt2 = 0; nt2 < 2; ++nt2) {
        const float bv = ba[(eid << 5) + nt2 * 16 + l16];
#pragma unroll
        for (int mt = 0; mt < 4; ++mt) {
            f32x4 c; c[0] = bv; c[1] = bv; c[2] = bv; c[3] = bv;
            acc2[mt][nt2] = c;
        }
    }

    // ---- expert-A GEMM: h2 = tanh(acc) restaged [d][sample]; 2 K-chunks ----
    const bf16x8* __restrict__ waeh = Wafh + (eid << 8);
    const bf16x8* __restrict__ wael = Wafl + (eid << 8);
#pragma unroll 1
    for (int c2 = 0; c2 < 2; ++c2) {
        if (c2) __syncthreads();
#pragma unroll
        for (int mt = 0; mt < 4; ++mt) {
#pragma unroll
            for (int ntl = 0; ntl < 2; ++ntl) {
#pragma unroll
                for (int r = 0; r < 4; ++r) {
                    const float h2 = fast_tanh(acc[mt][c2 * 2 + ntl][r]);
                    const int dl  = ntl * 16 + l16;
                    const int row = wv * 64 + mt * 16 + qd * 4 + r;
                    sbuf[dl * SA + row] = packsplit(h2);
                }
            }
        }
        __syncthreads();

        bf16x8 B2hi[2], B2lo[2];
#pragma unroll
        for (int nt2 = 0; nt2 < 2; ++nt2) {
            const int rec = (c2 * 2 + nt2) * 64 + qd * 16 + l16;
            B2hi[nt2] = waeh[rec];
            B2lo[nt2] = wael[rec];
        }
#pragma unroll
        for (int mt = 0; mt < 4; ++mt) {
            unsigned int a[8];
            const int mrow = wv * 64 + mt * 16 + l16;
#pragma unroll
            for (int j = 0; j < 8; ++j) a[j] = sbuf[(qd * 8 + j) * SA + mrow];
            bf16x8 Ahi, Alo;
            unpack8(a, Ahi, Alo);
#pragma unroll
            for (int nt2 = 0; nt2 < 2; ++nt2) {
                acc2[mt][nt2] = __builtin_amdgcn_mfma_f32_16x16x32_bf16(Ahi, B2hi[nt2], acc2[mt][nt2], 0, 0, 0);
                acc2[mt][nt2] = __builtin_amdgcn_mfma_f32_16x16x32_bf16(Ahi, B2lo[nt2], acc2[mt][nt2], 0, 0, 0);
                acc2[mt][nt2] = __builtin_amdgcn_mfma_f32_16x16x32_bf16(Alo, B2hi[nt2], acc2[mt][nt2], 0, 0, 0);
            }
        }
    }

    // ---- g = tanh(acc2) staged [sample][h], expert-B per-thread ----
    __syncthreads();
    float* g2 = (float*)sbuf;
#pragma unroll
    for (int mt = 0; mt < 4; ++mt) {
#pragma unroll
        for (int nt2 = 0; nt2 < 2; ++nt2) {
#pragma unroll
            for (int r = 0; r < 4; ++r) {
                const int row = wv * 64 + mt * 16 + qd * 4 + r;
                g2[row * SG + nt2 * 16 + l16] = fast_tanh(acc2[mt][nt2][r]);
            }
        }
    }
    __syncthreads();

    float gv[32];
    {
        const float4* grow = (const float4*)(g2 + tid * SG);
#pragma unroll
        for (int i = 0; i < 8; ++i) {
            float4 v = grow[i];
            gv[4 * i + 0] = v.x; gv[4 * i + 1] = v.y;
            gv[4 * i + 2] = v.z; gv[4 * i + 3] = v.w;
        }
    }

    const float* __restrict__ wbe = Wb + (eid << 6);
    float p0 = bb[2 * eid], p1 = bb[2 * eid + 1];
#pragma unroll
    for (int h = 0; h < 32; ++h) {
        p0 = fmaf(gv[h], wbe[2 * h + 0], p0);
        p1 = fmaf(gv[h], wbe[2 * h + 1], p1);
    }

    const float s = fmaf(p0, p0, fmaf(p1, p1, 1e-6f));
    const float inv = 1.0f / sqrtf(s);
    if (valid) {
        float2 o; o.x = p0 * inv; o.y = p1 * inv;
        ((float2*)out)[idx] = o;
    }
}

extern "C" void kernel_launch(void* const* d_in, const int* in_sizes, int n_in,
                              void* d_out, int out_size, void* d_ws, size_t ws_size,
                              hipStream_t stream) {
    const float* x  = (const float*)d_in[0];
    const int*   n  = (const int*)d_in[1];
    const int*   l  = (const int*)d_in[2];
    const int*   m  = (const int*)d_in[3];
    const float* W0 = (const float*)d_in[4];
    const float* b0 = (const float*)d_in[5];
    const float* W1 = (const float*)d_in[6];
    const float* b1 = (const float*)d_in[7];
    const float* Wa = (const float*)d_in[8];
    const float* ba = (const float*)d_in[9];
    const float* Wb = (const float*)d_in[10];
    const float* bb = (const float*)d_in[11];
    float* out = (float*)d_out;

    const int B = in_sizes[1];   // 262144

    // workspace layout (all segments 16B aligned)
    int*            perm = (int*)d_ws;                       // B
    int*            eids = perm + B;                         // B
    int*            bcnt = eids + B;                         // HB*NE = 3840
    int*            etot = bcnt + HB * NE;                   // 32
    unsigned short* W1fh = (unsigned short*)(etot + 32);     // 8192 u16
    unsigned short* W1fl = W1fh + 8192;                      // 8192 u16
    unsigned short* Wafh = W1fl + 8192;                      // 30*2048 u16
    unsigned short* Wafl = Wafh + NE * 2048;                 // 30*2048 u16

    hist_pack_kernel<<<HB + 1 + NE, 256, 0, stream>>>(
        n, l, m, eids, bcnt, W1, W1fh, W1fl, Wa, Wafh, Wafl, B);
    scatter_kernel<<<HB, 256, 0, stream>>>(eids, bcnt, etot, perm, B);
    wfc_kernel<<<MAXBLK, THREADS, 0, stream>>>(
        x, perm, etot, W0, b0,
        (const bf16x8*)W1fh, (const bf16x8*)W1fl, b1,
        (const bf16x8*)Wafh, (const bf16x8*)Wafl, ba, Wb, bb, out);
}

// Round 11
// 145.486 us; speedup vs baseline: 1.2090x; 1.2090x over previous
//
#include <hip/hip_runtime.h>
#include <math.h>

// WfcNN: B=262144.
//   h1 = tanh(x @ W0 + b0)            (B,128)
//   h2 = tanh(h1 @ W1 + b1)           (B,64)
//   g  = tanh(h2 . Wa[eid] + ba[eid]) (B,32)
//   psi= g . Wb[eid] + bb[eid]        (B,2) ; out = psi / sqrt(|psi|^2+1e-6)
//
// Round 11: REVERT compute to R9's validated kernel (56.8us) + keep R10 prep
// (no memset node, per-block hist counts, scatter derives scan itself).
// R10 lesson (repeat of R2): computing layer-2 A-frags in registers needs
// ~190 live regs under a ~170 cap -> scratch spill -> 160MB HBM traffic ->
// 87us. The LDS round-trip for A is what keeps live state small; keep it.
// R8 lesson: hipLaunchCooperativeKernel fails in this harness; off-limits.
// Both GEMMs on MFMA 3-pass split-bf16 (validated R5-R9, absmax pinned at
// the 2^-8 harness comparison floor).

#define THREADS 256
#define NE 30
#define HB 128
#define MAXBLK 1056
#define SA 259            // u32 row stride for [k][sample] staging (odd -> 2-way max)
#define SG 36             // f32 row stride for [sample][h] g staging

typedef short bf16x8 __attribute__((ext_vector_type(8)));
typedef float f32x4 __attribute__((ext_vector_type(4)));

__device__ __forceinline__ int expert_id(int nn, int ll, int mm) {
    return ((nn - 1) * nn * (2 * nn - 1)) / 6 + ll * ll + ll + mm;
}

// tanh(v) = 1 - 2/(exp2(2*log2e*v)+1); saturates correctly, no clamp.
__device__ __forceinline__ float fast_tanh(float v) {
    float e = __builtin_exp2f(v * 2.885390082f);
    return fmaf(-2.0f, __builtin_amdgcn_rcpf(e + 1.0f), 1.0f);
}

__device__ __forceinline__ unsigned int f2b(float f) {   // f32 -> bf16 RNE
    unsigned int u = __float_as_uint(f);
    return (u + 0x7fffu + ((u >> 16) & 1u)) >> 16;
}
__device__ __forceinline__ float b2f(unsigned int b) {
    return __uint_as_float(b << 16);
}
// runtime split: RNE hi, truncated lo; packed (lo16<<16)|hi16
__device__ __forceinline__ unsigned int packsplit(float v) {
    const unsigned int hb = f2b(v);
    const float lo = v - b2f(hb);
    return (__float_as_uint(lo) & 0xffff0000u) | hb;
}

union U8 { unsigned int u[4]; bf16x8 v; };
// packed words -> hi-plane / lo-plane bf16x8 (v_perm_b32 byte selects)
__device__ __forceinline__ void unpack8(const unsigned int* w, bf16x8& hi, bf16x8& lo) {
    U8 H, L;
#pragma unroll
    for (int i = 0; i < 4; ++i) {
        H.u[i] = __builtin_amdgcn_perm(w[2 * i + 1], w[2 * i], 0x05040100u);
        L.u[i] = __builtin_amdgcn_perm(w[2 * i + 1], w[2 * i], 0x07060302u);
    }
    hi = H.v; lo = L.v;
}

// ---- K1: per-block hist + eid cache + weight split-packing ----
__global__ void hist_pack_kernel(const int* __restrict__ nq, const int* __restrict__ lq,
                                 const int* __restrict__ mq,
                                 int* __restrict__ eids, int* __restrict__ bcnt,
                                 const float* __restrict__ W1,
                                 unsigned short* __restrict__ W1fh, unsigned short* __restrict__ W1fl,
                                 const float* __restrict__ Wa,
                                 unsigned short* __restrict__ Wafh, unsigned short* __restrict__ Wafl,
                                 int B) {
    const int tid = threadIdx.x;
    const int bx = blockIdx.x;
    if (bx < HB) {
        __shared__ int h[NE];
        if (tid < NE) h[tid] = 0;
        __syncthreads();
        const int per = B / HB, base = bx * per;
        for (int i = tid; i < per; i += blockDim.x) {
            const int e = expert_id(nq[base + i], lq[base + i], mq[base + i]);
            eids[base + i] = e;
            atomicAdd(&h[e], 1);
        }
        __syncthreads();
        if (tid < NE) bcnt[bx * NE + tid] = h[tid];
    } else if (bx == HB) {
        // W1 (128,64) -> hi/lo planes in B-frag order (rec=((c*4+nt)*4+qd)*16+l16)
        for (int i = tid; i < 8192; i += blockDim.x) {
            const int j = i & 7, s = (i >> 3) & 15, q = (i >> 7) & 3;
            const int nt = (i >> 9) & 3, c = i >> 11;
            const int k = c * 32 + q * 8 + j, n = nt * 16 + s;
            const float w = W1[k * 64 + n];
            const unsigned int hb = f2b(w);
            W1fh[i] = (unsigned short)hb;
            W1fl[i] = (unsigned short)f2b(w - b2f(hb));
        }
    } else {
        // Wa[e] (64,32) -> hi/lo planes (rec=((c2*2+nt2)*4+qd)*16+l16)
        const int e = bx - HB - 1;
        for (int i = tid; i < 2048; i += blockDim.x) {
            const int j = i & 7, s = (i >> 3) & 15, q = (i >> 7) & 3;
            const int nt2 = (i >> 9) & 1, c2 = (i >> 10) & 1;
            const int d = c2 * 32 + q * 8 + j, hh = nt2 * 16 + s;
            const float w = Wa[e * 2048 + d * 32 + hh];
            const unsigned int hb = f2b(w);
            Wafh[e * 2048 + i] = (unsigned short)hb;
            Wafl[e * 2048 + i] = (unsigned short)f2b(w - b2f(hb));
        }
    }
}

// ---- K2: scatter; derives scan + own bases from count table; publishes etot ----
__global__ void scatter_kernel(const int* __restrict__ eids, const int* __restrict__ bcnt,
                               int* __restrict__ etot, int* __restrict__ perm, int B) {
    __shared__ int sh[HB * NE];
    __shared__ int esrt[NE], bb[NE], lcnt[NE], tot[NE];
    const int tid = threadIdx.x;
    for (int i = tid; i < HB * NE; i += blockDim.x) sh[i] = bcnt[i];
    if (tid < NE) lcnt[tid] = 0;
    __syncthreads();
    if (tid < NE) {
        int pre = 0, t = 0;
        for (int b = 0; b < HB; ++b) {
            const int v = sh[b * NE + tid];
            if (b < (int)blockIdx.x) pre += v;
            t += v;
        }
        tot[tid] = t;
        bb[tid] = pre;
        if (blockIdx.x == 0) etot[tid] = t;     // publish for wfc
    }
    __syncthreads();
    if (tid == 0) {
        int es = 0;
        for (int e = 0; e < NE; ++e) { esrt[e] = es; es += tot[e]; }
    }
    __syncthreads();
    const int per = B / gridDim.x;
    const int blk = blockIdx.x * per;
    for (int i = tid; i < per; i += blockDim.x) {
        const int idx = blk + i;
        const int e = eids[idx];
        const int r = atomicAdd(&lcnt[e], 1);
        perm[esrt[e] + bb[e] + r] = idx;
    }
}

// ---- K3: fused MLP; layer2 + expert-A on MFMA (3-pass split-bf16) ----
__global__ __launch_bounds__(THREADS, 3) void wfc_kernel(
    const float* __restrict__ x, const int* __restrict__ perm,
    const int* __restrict__ etot,
    const float* __restrict__ W0, const float* __restrict__ b0,
    const bf16x8* __restrict__ W1fh, const bf16x8* __restrict__ W1fl,
    const float* __restrict__ b1,
    const bf16x8* __restrict__ Wafh, const bf16x8* __restrict__ Wafl,
    const float* __restrict__ ba,
    const float* __restrict__ Wb, const float* __restrict__ bb,
    float* __restrict__ out)
{
    __shared__ unsigned int sbuf[9216];      // 36,864 B staging

    // derive (eid, start, cnt) from etot: uniform scalar 30-iter scan
    int eid = -1, start = 0, cnt = 0;
    {
        int cum = 0, es = 0;
#pragma unroll 1
        for (int e = 0; e < NE; ++e) {
            const int t = etot[e];
            const int nb = (t + THREADS - 1) >> 8;
            if ((int)blockIdx.x < cum + nb) {
                const int seg = blockIdx.x - cum;
                eid = e; start = es + seg * THREADS; cnt = min(THREADS, t - seg * THREADS);
                break;
            }
            cum += nb; es += t;
        }
    }
    if (eid < 0) return;
    eid = __builtin_amdgcn_readfirstlane(eid);

    const int tid = threadIdx.x;
    const bool valid = tid < cnt;
    const int idx = perm[start + (valid ? tid : 0)];

    const int lane = tid & 63;
    const int wv   = tid >> 6;
    const int qd   = lane >> 4;
    const int l16  = lane & 15;

    const float x0 = x[idx * 3 + 0];
    const float x1 = x[idx * 3 + 1];
    const float x2 = x[idx * 3 + 2];

    // ---- layer 2 accumulators, init b1 (C layout: col = l16) ----
    f32x4 acc[4][4];
#pragma unroll
    for (int nt = 0; nt < 4; ++nt) {
        const float bv = b1[nt * 16 + l16];
#pragma unroll
        for (int mt = 0; mt < 4; ++mt) {
            f32x4 c; c[0] = bv; c[1] = bv; c[2] = bv; c[3] = bv;
            acc[mt][nt] = c;
        }
    }

    // ---- layer-2 GEMM: 4 K-chunks of 32 ----
    for (int c = 0; c < 4; ++c) {
        if (c) __syncthreads();
#pragma unroll
        for (int kk = 0; kk < 32; ++kk) {
            const int k = c * 32 + kk;
            const float pre = fmaf(x0, W0[k], fmaf(x1, W0[128 + k], fmaf(x2, W0[256 + k], b0[k])));
            sbuf[kk * SA + tid] = packsplit(fast_tanh(pre));
        }
        __syncthreads();

        bf16x8 Bhi[4], Blo[4];
#pragma unroll
        for (int nt = 0; nt < 4; ++nt) {
            const int rec = (c * 4 + nt) * 64 + qd * 16 + l16;
            Bhi[nt] = W1fh[rec];
            Blo[nt] = W1fl[rec];
        }
#pragma unroll
        for (int mt = 0; mt < 4; ++mt) {
            unsigned int a[8];
            const int mrow = wv * 64 + mt * 16 + l16;
#pragma unroll
            for (int j = 0; j < 8; ++j) a[j] = sbuf[(qd * 8 + j) * SA + mrow];
            bf16x8 Ahi, Alo;
            unpack8(a, Ahi, Alo);
#pragma unroll
            for (int nt = 0; nt < 4; ++nt) {
                acc[mt][nt] = __builtin_amdgcn_mfma_f32_16x16x32_bf16(Ahi, Bhi[nt], acc[mt][nt], 0, 0, 0);
                acc[mt][nt] = __builtin_amdgcn_mfma_f32_16x16x32_bf16(Ahi, Blo[nt], acc[mt][nt], 0, 0, 0);
                acc[mt][nt] = __builtin_amdgcn_mfma_f32_16x16x32_bf16(Alo, Bhi[nt], acc[mt][nt], 0, 0, 0);
            }
        }
    }

    // ---- expert-A accumulators, init ba ----
    f32x4 acc2[4][2];
#pragma unroll
    for (int nt2 = 0; nt2 < 2; ++nt2) {
        const float bv = ba[(eid << 5) + nt2 * 16 + l16];
#pragma unroll
        for (int mt = 0; mt < 4; ++mt) {
            f32x4 c; c[0] = bv; c[1] = bv; c[2] = bv; c[3] = bv;
            acc2[mt][nt2] = c;
        }
    }

    // ---- expert-A GEMM: h2 = tanh(acc) restaged [d][sample]; 2 K-chunks ----
    const bf16x8* __restrict__ waeh = Wafh + (eid << 8);
    const bf16x8* __restrict__ wael = Wafl + (eid << 8);
    for (int c2 = 0; c2 < 2; ++c2) {
        __syncthreads();
#pragma unroll
        for (int mt = 0; mt < 4; ++mt) {
#pragma unroll
            for (int ntl = 0; ntl < 2; ++ntl) {
#pragma unroll
                for (int r = 0; r < 4; ++r) {
                    const float h2 = fast_tanh(acc[mt][c2 * 2 + ntl][r]);
                    const int dl  = ntl * 16 + l16;
                    const int row = wv * 64 + mt * 16 + qd * 4 + r;
                    sbuf[dl * SA + row] = packsplit(h2);
                }
            }
        }
        __syncthreads();

        bf16x8 B2hi[2], B2lo[2];
#pragma unroll
        for (int nt2 = 0; nt2 < 2; ++nt2) {
            const int rec = (c2 * 2 + nt2) * 64 + qd * 16 + l16;
            B2hi[nt2] = waeh[rec];
            B2lo[nt2] = wael[rec];
        }
#pragma unroll
        for (int mt = 0; mt < 4; ++mt) {
            unsigned int a[8];
            const int mrow = wv * 64 + mt * 16 + l16;
#pragma unroll
            for (int j = 0; j < 8; ++j) a[j] = sbuf[(qd * 8 + j) * SA + mrow];
            bf16x8 Ahi, Alo;
            unpack8(a, Ahi, Alo);
#pragma unroll
            for (int nt2 = 0; nt2 < 2; ++nt2) {
                acc2[mt][nt2] = __builtin_amdgcn_mfma_f32_16x16x32_bf16(Ahi, B2hi[nt2], acc2[mt][nt2], 0, 0, 0);
                acc2[mt][nt2] = __builtin_amdgcn_mfma_f32_16x16x32_bf16(Ahi, B2lo[nt2], acc2[mt][nt2], 0, 0, 0);
                acc2[mt][nt2] = __builtin_amdgcn_mfma_f32_16x16x32_bf16(Alo, B2hi[nt2], acc2[mt][nt2], 0, 0, 0);
            }
        }
    }

    // ---- g = tanh(acc2) staged [sample][h], expert-B per-thread ----
    __syncthreads();
    float* g2 = (float*)sbuf;
#pragma unroll
    for (int mt = 0; mt < 4; ++mt) {
#pragma unroll
        for (int nt2 = 0; nt2 < 2; ++nt2) {
#pragma unroll
            for (int r = 0; r < 4; ++r) {
                const int row = wv * 64 + mt * 16 + qd * 4 + r;
                g2[row * SG + nt2 * 16 + l16] = fast_tanh(acc2[mt][nt2][r]);
            }
        }
    }
    __syncthreads();

    float gv[32];
    {
        const float4* grow = (const float4*)(g2 + tid * SG);
#pragma unroll
        for (int i = 0; i < 8; ++i) {
            float4 v = grow[i];
            gv[4 * i + 0] = v.x; gv[4 * i + 1] = v.y;
            gv[4 * i + 2] = v.z; gv[4 * i + 3] = v.w;
        }
    }

    const float* __restrict__ wbe = Wb + (eid << 6);
    float p0 = bb[2 * eid], p1 = bb[2 * eid + 1];
#pragma unroll
    for (int h = 0; h < 32; ++h) {
        p0 = fmaf(gv[h], wbe[2 * h + 0], p0);
        p1 = fmaf(gv[h], wbe[2 * h + 1], p1);
    }

    const float s = fmaf(p0, p0, fmaf(p1, p1, 1e-6f));
    const float inv = 1.0f / sqrtf(s);
    if (valid) {
        float2 o; o.x = p0 * inv; o.y = p1 * inv;
        ((float2*)out)[idx] = o;
    }
}

extern "C" void kernel_launch(void* const* d_in, const int* in_sizes, int n_in,
                              void* d_out, int out_size, void* d_ws, size_t ws_size,
                              hipStream_t stream) {
    const float* x  = (const float*)d_in[0];
    const int*   n  = (const int*)d_in[1];
    const int*   l  = (const int*)d_in[2];
    const int*   m  = (const int*)d_in[3];
    const float* W0 = (const float*)d_in[4];
    const float* b0 = (const float*)d_in[5];
    const float* W1 = (const float*)d_in[6];
    const float* b1 = (const float*)d_in[7];
    const float* Wa = (const float*)d_in[8];
    const float* ba = (const float*)d_in[9];
    const float* Wb = (const float*)d_in[10];
    const float* bb = (const float*)d_in[11];
    float* out = (float*)d_out;

    const int B = in_sizes[1];   // 262144

    // workspace layout (all segments 16B aligned)
    int*            perm = (int*)d_ws;                       // B
    int*            eids = perm + B;                         // B
    int*            bcnt = eids + B;                         // HB*NE = 3840
    int*            etot = bcnt + HB * NE;                   // 32
    unsigned short* W1fh = (unsigned short*)(etot + 32);     // 8192 u16
    unsigned short* W1fl = W1fh + 8192;                      // 8192 u16
    unsigned short* Wafh = W1fl + 8192;                      // 30*2048 u16
    unsigned short* Wafl = Wafh + NE * 2048;                 // 30*2048 u16

    hist_pack_kernel<<<HB + 1 + NE, 256, 0, stream>>>(
        n, l, m, eids, bcnt, W1, W1fh, W1fl, Wa, Wafh, Wafl, B);
    scatter_kernel<<<HB, 256, 0, stream>>>(eids, bcnt, etot, perm, B);
    wfc_kernel<<<MAXBLK, THREADS, 0, stream>>>(
        x, perm, etot, W0, b0,
        (const bf16x8*)W1fh, (const bf16x8*)W1fl, b1,
        (const bf16x8*)Wafh, (const bf16x8*)Wafl, ba, Wb, bb, out);
}

// Round 13
// 142.830 us; speedup vs baseline: 1.2315x; 1.0186x over previous
//
#include <hip/hip_runtime.h>
#include <math.h>

// WfcNN: B=262144.
//   h1 = tanh(x @ W0 + b0)            (B,128)
//   h2 = tanh(h1 @ W1 + b1)           (B,64)
//   g  = tanh(h2 . Wa[eid] + ba[eid]) (B,32)
//   psi= g . Wb[eid] + bb[eid]        (B,2) ; out = psi / sqrt(|psi|^2+1e-6)
//
// Round 13: near-barrier-free wfc (R12 fix). The layer-2 staging, h2-restage
// and their fragment reads all use the SAME [row][col] stride-SA layout with
// column = sample in the wave's private 64-slice -> no cross-wave dependency,
// and per-wave LDS ops are pipeline-ordered (intra-wave WAR safe). Those 8
// barriers stay deleted. BUT the g-stage re-layouts sbuf as [sample][h]
// (stride SG): wave w writes float idx [2304w, 2304w+2304), aliasing rows
// dl=0..8 of ALL columns of the [d][sample] layout -- that raced with slower
// waves' expert-A reads in R12 (NaN). ONE __syncthreads() before the g-stage
// closes it. Zero arithmetic change vs R9/R11.
// R10/R2 lesson: register-resident A-frags spill; keep the LDS trip.
// R8 lesson: hipLaunchCooperativeKernel fails in this harness; off-limits.

#define THREADS 256
#define NE 30
#define HB 128
#define MAXBLK 1056
#define SA 259            // u32 row stride for [k][sample] staging (odd -> 2-way max)
#define SG 36             // f32 row stride for [sample][h] g staging

typedef short bf16x8 __attribute__((ext_vector_type(8)));
typedef float f32x4 __attribute__((ext_vector_type(4)));

__device__ __forceinline__ int expert_id(int nn, int ll, int mm) {
    return ((nn - 1) * nn * (2 * nn - 1)) / 6 + ll * ll + ll + mm;
}

// tanh(v) = 1 - 2/(exp2(2*log2e*v)+1); saturates correctly, no clamp.
__device__ __forceinline__ float fast_tanh(float v) {
    float e = __builtin_exp2f(v * 2.885390082f);
    return fmaf(-2.0f, __builtin_amdgcn_rcpf(e + 1.0f), 1.0f);
}

__device__ __forceinline__ unsigned int f2b(float f) {   // f32 -> bf16 RNE
    unsigned int u = __float_as_uint(f);
    return (u + 0x7fffu + ((u >> 16) & 1u)) >> 16;
}
__device__ __forceinline__ float b2f(unsigned int b) {
    return __uint_as_float(b << 16);
}
// runtime split: RNE hi, truncated lo; packed (lo16<<16)|hi16
__device__ __forceinline__ unsigned int packsplit(float v) {
    const unsigned int hb = f2b(v);
    const float lo = v - b2f(hb);
    return (__float_as_uint(lo) & 0xffff0000u) | hb;
}

union U8 { unsigned int u[4]; bf16x8 v; };
// packed words -> hi-plane / lo-plane bf16x8 (v_perm_b32 byte selects)
__device__ __forceinline__ void unpack8(const unsigned int* w, bf16x8& hi, bf16x8& lo) {
    U8 H, L;
#pragma unroll
    for (int i = 0; i < 4; ++i) {
        H.u[i] = __builtin_amdgcn_perm(w[2 * i + 1], w[2 * i], 0x05040100u);
        L.u[i] = __builtin_amdgcn_perm(w[2 * i + 1], w[2 * i], 0x07060302u);
    }
    hi = H.v; lo = L.v;
}

// ---- K1: per-block hist + eid cache + weight split-packing ----
__global__ void hist_pack_kernel(const int* __restrict__ nq, const int* __restrict__ lq,
                                 const int* __restrict__ mq,
                                 int* __restrict__ eids, int* __restrict__ bcnt,
                                 const float* __restrict__ W1,
                                 unsigned short* __restrict__ W1fh, unsigned short* __restrict__ W1fl,
                                 const float* __restrict__ Wa,
                                 unsigned short* __restrict__ Wafh, unsigned short* __restrict__ Wafl,
                                 int B) {
    const int tid = threadIdx.x;
    const int bx = blockIdx.x;
    if (bx < HB) {
        __shared__ int h[NE];
        if (tid < NE) h[tid] = 0;
        __syncthreads();
        const int per = B / HB, base = bx * per;
        for (int i = tid; i < per; i += blockDim.x) {
            const int e = expert_id(nq[base + i], lq[base + i], mq[base + i]);
            eids[base + i] = e;
            atomicAdd(&h[e], 1);
        }
        __syncthreads();
        if (tid < NE) bcnt[bx * NE + tid] = h[tid];
    } else if (bx == HB) {
        // W1 (128,64) -> hi/lo planes in B-frag order (rec=((c*4+nt)*4+qd)*16+l16)
        for (int i = tid; i < 8192; i += blockDim.x) {
            const int j = i & 7, s = (i >> 3) & 15, q = (i >> 7) & 3;
            const int nt = (i >> 9) & 3, c = i >> 11;
            const int k = c * 32 + q * 8 + j, n = nt * 16 + s;
            const float w = W1[k * 64 + n];
            const unsigned int hb = f2b(w);
            W1fh[i] = (unsigned short)hb;
            W1fl[i] = (unsigned short)f2b(w - b2f(hb));
        }
    } else {
        // Wa[e] (64,32) -> hi/lo planes (rec=((c2*2+nt2)*4+qd)*16+l16)
        const int e = bx - HB - 1;
        for (int i = tid; i < 2048; i += blockDim.x) {
            const int j = i & 7, s = (i >> 3) & 15, q = (i >> 7) & 3;
            const int nt2 = (i >> 9) & 1, c2 = (i >> 10) & 1;
            const int d = c2 * 32 + q * 8 + j, hh = nt2 * 16 + s;
            const float w = Wa[e * 2048 + d * 32 + hh];
            const unsigned int hb = f2b(w);
            Wafh[e * 2048 + i] = (unsigned short)hb;
            Wafl[e * 2048 + i] = (unsigned short)f2b(w - b2f(hb));
        }
    }
}

// ---- K2: scatter; derives scan + own bases from count table; publishes etot ----
__global__ void scatter_kernel(const int* __restrict__ eids, const int* __restrict__ bcnt,
                               int* __restrict__ etot, int* __restrict__ perm, int B) {
    __shared__ int sh[HB * NE];
    __shared__ int esrt[NE], bb[NE], lcnt[NE], tot[NE];
    const int tid = threadIdx.x;
    for (int i = tid; i < HB * NE; i += blockDim.x) sh[i] = bcnt[i];
    if (tid < NE) lcnt[tid] = 0;
    __syncthreads();
    if (tid < NE) {
        int pre = 0, t = 0;
        for (int b = 0; b < HB; ++b) {
            const int v = sh[b * NE + tid];
            if (b < (int)blockIdx.x) pre += v;
            t += v;
        }
        tot[tid] = t;
        bb[tid] = pre;
        if (blockIdx.x == 0) etot[tid] = t;     // publish for wfc
    }
    __syncthreads();
    if (tid == 0) {
        int es = 0;
        for (int e = 0; e < NE; ++e) { esrt[e] = es; es += tot[e]; }
    }
    __syncthreads();
    const int per = B / gridDim.x;
    const int blk = blockIdx.x * per;
    for (int i = tid; i < per; i += blockDim.x) {
        const int idx = blk + i;
        const int e = eids[idx];
        const int r = atomicAdd(&lcnt[e], 1);
        perm[esrt[e] + bb[e] + r] = idx;
    }
}

// ---- K3: fused MLP; MFMA GEMMs; single barrier (before g re-layout) ----
__global__ __launch_bounds__(THREADS, 3) void wfc_kernel(
    const float* __restrict__ x, const int* __restrict__ perm,
    const int* __restrict__ etot,
    const float* __restrict__ W0, const float* __restrict__ b0,
    const bf16x8* __restrict__ W1fh, const bf16x8* __restrict__ W1fl,
    const float* __restrict__ b1,
    const bf16x8* __restrict__ Wafh, const bf16x8* __restrict__ Wafl,
    const float* __restrict__ ba,
    const float* __restrict__ Wb, const float* __restrict__ bb,
    float* __restrict__ out)
{
    __shared__ unsigned int sbuf[9216];      // 36,864 B staging (wave-sliced)

    // derive (eid, start, cnt) from etot: uniform scalar 30-iter scan
    int eid = -1, start = 0, cnt = 0;
    {
        int cum = 0, es = 0;
#pragma unroll 1
        for (int e = 0; e < NE; ++e) {
            const int t = etot[e];
            const int nb = (t + THREADS - 1) >> 8;
            if ((int)blockIdx.x < cum + nb) {
                const int seg = blockIdx.x - cum;
                eid = e; start = es + seg * THREADS; cnt = min(THREADS, t - seg * THREADS);
                break;
            }
            cum += nb; es += t;
        }
    }
    if (eid < 0) return;
    eid = __builtin_amdgcn_readfirstlane(eid);

    const int tid = threadIdx.x;
    const bool valid = tid < cnt;
    const int idx = perm[start + (valid ? tid : 0)];

    const int lane = tid & 63;
    const int wv   = tid >> 6;
    const int qd   = lane >> 4;
    const int l16  = lane & 15;

    const float x0 = x[idx * 3 + 0];
    const float x1 = x[idx * 3 + 1];
    const float x2 = x[idx * 3 + 2];

    // ---- layer 2 accumulators, init b1 (C layout: col = l16) ----
    f32x4 acc[4][4];
#pragma unroll
    for (int nt = 0; nt < 4; ++nt) {
        const float bv = b1[nt * 16 + l16];
#pragma unroll
        for (int mt = 0; mt < 4; ++mt) {
            f32x4 c; c[0] = bv; c[1] = bv; c[2] = bv; c[3] = bv;
            acc[mt][nt] = c;
        }
    }

    // ---- layer-2 GEMM: 4 K-chunks of 32 (wave-private staging, no barriers) ----
    for (int c = 0; c < 4; ++c) {
#pragma unroll
        for (int kk = 0; kk < 32; ++kk) {
            const int k = c * 32 + kk;
            const float pre = fmaf(x0, W0[k], fmaf(x1, W0[128 + k], fmaf(x2, W0[256 + k], b0[k])));
            sbuf[kk * SA + tid] = packsplit(fast_tanh(pre));
        }

        bf16x8 Bhi[4], Blo[4];
#pragma unroll
        for (int nt = 0; nt < 4; ++nt) {
            const int rec = (c * 4 + nt) * 64 + qd * 16 + l16;
            Bhi[nt] = W1fh[rec];
            Blo[nt] = W1fl[rec];
        }
#pragma unroll
        for (int mt = 0; mt < 4; ++mt) {
            unsigned int a[8];
            const int mrow = wv * 64 + mt * 16 + l16;
#pragma unroll
            for (int j = 0; j < 8; ++j) a[j] = sbuf[(qd * 8 + j) * SA + mrow];
            bf16x8 Ahi, Alo;
            unpack8(a, Ahi, Alo);
#pragma unroll
            for (int nt = 0; nt < 4; ++nt) {
                acc[mt][nt] = __builtin_amdgcn_mfma_f32_16x16x32_bf16(Ahi, Bhi[nt], acc[mt][nt], 0, 0, 0);
                acc[mt][nt] = __builtin_amdgcn_mfma_f32_16x16x32_bf16(Ahi, Blo[nt], acc[mt][nt], 0, 0, 0);
                acc[mt][nt] = __builtin_amdgcn_mfma_f32_16x16x32_bf16(Alo, Bhi[nt], acc[mt][nt], 0, 0, 0);
            }
        }
    }

    // ---- expert-A accumulators, init ba ----
    f32x4 acc2[4][2];
#pragma unroll
    for (int nt2 = 0; nt2 < 2; ++nt2) {
        const float bv = ba[(eid << 5) + nt2 * 16 + l16];
#pragma unroll
        for (int mt = 0; mt < 4; ++mt) {
            f32x4 c; c[0] = bv; c[1] = bv; c[2] = bv; c[3] = bv;
            acc2[mt][nt2] = c;
        }
    }

    // ---- expert-A GEMM: h2 restaged [d][sample]; 2 K-chunks; no barriers ----
    const bf16x8* __restrict__ waeh = Wafh + (eid << 8);
    const bf16x8* __restrict__ wael = Wafl + (eid << 8);
    for (int c2 = 0; c2 < 2; ++c2) {
#pragma unroll
        for (int mt = 0; mt < 4; ++mt) {
#pragma unroll
            for (int ntl = 0; ntl < 2; ++ntl) {
#pragma unroll
                for (int r = 0; r < 4; ++r) {
                    const float h2 = fast_tanh(acc[mt][c2 * 2 + ntl][r]);
                    const int dl  = ntl * 16 + l16;
                    const int row = wv * 64 + mt * 16 + qd * 4 + r;
                    sbuf[dl * SA + row] = packsplit(h2);
                }
            }
        }

        bf16x8 B2hi[2], B2lo[2];
#pragma unroll
        for (int nt2 = 0; nt2 < 2; ++nt2) {
            const int rec = (c2 * 2 + nt2) * 64 + qd * 16 + l16;
            B2hi[nt2] = waeh[rec];
            B2lo[nt2] = wael[rec];
        }
#pragma unroll
        for (int mt = 0; mt < 4; ++mt) {
            unsigned int a[8];
            const int mrow = wv * 64 + mt * 16 + l16;
#pragma unroll
            for (int j = 0; j < 8; ++j) a[j] = sbuf[(qd * 8 + j) * SA + mrow];
            bf16x8 Ahi, Alo;
            unpack8(a, Ahi, Alo);
#pragma unroll
            for (int nt2 = 0; nt2 < 2; ++nt2) {
                acc2[mt][nt2] = __builtin_amdgcn_mfma_f32_16x16x32_bf16(Ahi, B2hi[nt2], acc2[mt][nt2], 0, 0, 0);
                acc2[mt][nt2] = __builtin_amdgcn_mfma_f32_16x16x32_bf16(Ahi, B2lo[nt2], acc2[mt][nt2], 0, 0, 0);
                acc2[mt][nt2] = __builtin_amdgcn_mfma_f32_16x16x32_bf16(Alo, B2hi[nt2], acc2[mt][nt2], 0, 0, 0);
            }
        }
    }

    // ---- THE one barrier: g-stage re-layouts sbuf ([sample][h], stride SG),
    // whose per-wave write window [2304*wv, 2304*wv+2304) floats aliases rows
    // dl=0..8 of ALL waves' columns in the [d][sample] layout above. Must
    // drain every wave's expert-A reads before overwriting. (R12's NaN.)
    __syncthreads();
    float* g2 = (float*)sbuf;
#pragma unroll
    for (int mt = 0; mt < 4; ++mt) {
#pragma unroll
        for (int nt2 = 0; nt2 < 2; ++nt2) {
#pragma unroll
            for (int r = 0; r < 4; ++r) {
                const int row = wv * 64 + mt * 16 + qd * 4 + r;
                g2[row * SG + nt2 * 16 + l16] = fast_tanh(acc2[mt][nt2][r]);
            }
        }
    }

    float gv[32];
    {
        const float4* grow = (const float4*)(g2 + tid * SG);
#pragma unroll
        for (int i = 0; i < 8; ++i) {
            float4 v = grow[i];
            gv[4 * i + 0] = v.x; gv[4 * i + 1] = v.y;
            gv[4 * i + 2] = v.z; gv[4 * i + 3] = v.w;
        }
    }

    const float* __restrict__ wbe = Wb + (eid << 6);
    float p0 = bb[2 * eid], p1 = bb[2 * eid + 1];
#pragma unroll
    for (int h = 0; h < 32; ++h) {
        p0 = fmaf(gv[h], wbe[2 * h + 0], p0);
        p1 = fmaf(gv[h], wbe[2 * h + 1], p1);
    }

    const float s = fmaf(p0, p0, fmaf(p1, p1, 1e-6f));
    const float inv = 1.0f / sqrtf(s);
    if (valid) {
        float2 o; o.x = p0 * inv; o.y = p1 * inv;
        ((float2*)out)[idx] = o;
    }
}

extern "C" void kernel_launch(void* const* d_in, const int* in_sizes, int n_in,
                              void* d_out, int out_size, void* d_ws, size_t ws_size,
                              hipStream_t stream) {
    const float* x  = (const float*)d_in[0];
    const int*   n  = (const int*)d_in[1];
    const int*   l  = (const int*)d_in[2];
    const int*   m  = (const int*)d_in[3];
    const float* W0 = (const float*)d_in[4];
    const float* b0 = (const float*)d_in[5];
    const float* W1 = (const float*)d_in[6];
    const float* b1 = (const float*)d_in[7];
    const float* Wa = (const float*)d_in[8];
    const float* ba = (const float*)d_in[9];
    const float* Wb = (const float*)d_in[10];
    const float* bb = (const float*)d_in[11];
    float* out = (float*)d_out;

    const int B = in_sizes[1];   // 262144

    // workspace layout (all segments 16B aligned)
    int*            perm = (int*)d_ws;                       // B
    int*            eids = perm + B;                         // B
    int*            bcnt = eids + B;                         // HB*NE = 3840
    int*            etot = bcnt + HB * NE;                   // 32
    unsigned short* W1fh = (unsigned short*)(etot + 32);     // 8192 u16
    unsigned short* W1fl = W1fh + 8192;                      // 8192 u16
    unsigned short* Wafh = W1fl + 8192;                      // 30*2048 u16
    unsigned short* Wafl = Wafh + NE * 2048;                 // 30*2048 u16

    hist_pack_kernel<<<HB + 1 + NE, 256, 0, stream>>>(
        n, l, m, eids, bcnt, W1, W1fh, W1fl, Wa, Wafh, Wafl, B);
    scatter_kernel<<<HB, 256, 0, stream>>>(eids, bcnt, etot, perm, B);
    wfc_kernel<<<MAXBLK, THREADS, 0, stream>>>(
        x, perm, etot, W0, b0,
        (const bf16x8*)W1fh, (const bf16x8*)W1fl, b1,
        (const bf16x8*)Wafh, (const bf16x8*)Wafl, ba, Wb, bb, out);
}

// Round 14
// 142.721 us; speedup vs baseline: 1.2325x; 1.0008x over previous
//
#include <hip/hip_runtime.h>
#include <math.h>

// WfcNN: B=262144.
//   h1 = tanh(x @ W0 + b0)            (B,128)
//   h2 = tanh(h1 @ W1 + b1)           (B,64)
//   g  = tanh(h2 . Wa[eid] + ba[eid]) (B,32)
//   psi= g . Wb[eid] + bb[eid]        (B,2) ; out = psi / sqrt(|psi|^2+1e-6)
//
// Round 14: row-per-sample LDS staging (stride 36 u32, 144B rows).
//  - [sample][k] layout -> layer-2 staging: 8x ds_write_b128 + 8x
//    ds_read_b128 per wave per chunk (was 64+32 b32). Expert-A reads b128.
//    Bank-audited conflict-free (b128 lanes span disjoint bank quads).
//  - ALL phases (stage, h2 restage, g stage, g read) now share the same
//    stride-36 row layout; every LDS access is in rows [64wv, 64wv+64) ->
//    strictly wave-private -> ZERO barriers (R12's race was cross-layout
//    aliasing, which no longer exists; same-wave DS in-order is validated
//    by R13's barrier-free WAR hazards passing).
//  - Fragment bit-patterns identical -> absmax must stay 0.00390625.
// R10/R2 lesson: register-resident A-frags spill; keep the LDS trip.
// R8 lesson: hipLaunchCooperativeKernel fails in this harness; off-limits.

#define THREADS 256
#define NE 30
#define HB 128
#define MAXBLK 1056
#define SR 36             // u32 row stride for ALL staging ([sample][col]); 144B rows

typedef short bf16x8 __attribute__((ext_vector_type(8)));
typedef float f32x4 __attribute__((ext_vector_type(4)));

__device__ __forceinline__ int expert_id(int nn, int ll, int mm) {
    return ((nn - 1) * nn * (2 * nn - 1)) / 6 + ll * ll + ll + mm;
}

// tanh(v) = 1 - 2/(exp2(2*log2e*v)+1); saturates correctly, no clamp.
__device__ __forceinline__ float fast_tanh(float v) {
    float e = __builtin_exp2f(v * 2.885390082f);
    return fmaf(-2.0f, __builtin_amdgcn_rcpf(e + 1.0f), 1.0f);
}

__device__ __forceinline__ unsigned int f2b(float f) {   // f32 -> bf16 RNE
    unsigned int u = __float_as_uint(f);
    return (u + 0x7fffu + ((u >> 16) & 1u)) >> 16;
}
__device__ __forceinline__ float b2f(unsigned int b) {
    return __uint_as_float(b << 16);
}
// runtime split: RNE hi, truncated lo; packed (lo16<<16)|hi16
__device__ __forceinline__ unsigned int packsplit(float v) {
    const unsigned int hb = f2b(v);
    const float lo = v - b2f(hb);
    return (__float_as_uint(lo) & 0xffff0000u) | hb;
}

union U8 { unsigned int u[4]; bf16x8 v; };
// packed words -> hi-plane / lo-plane bf16x8 (v_perm_b32 byte selects)
__device__ __forceinline__ void unpack8(const unsigned int* w, bf16x8& hi, bf16x8& lo) {
    U8 H, L;
#pragma unroll
    for (int i = 0; i < 4; ++i) {
        H.u[i] = __builtin_amdgcn_perm(w[2 * i + 1], w[2 * i], 0x05040100u);
        L.u[i] = __builtin_amdgcn_perm(w[2 * i + 1], w[2 * i], 0x07060302u);
    }
    hi = H.v; lo = L.v;
}

// ---- K1: per-block hist + eid cache + weight split-packing ----
__global__ void hist_pack_kernel(const int* __restrict__ nq, const int* __restrict__ lq,
                                 const int* __restrict__ mq,
                                 int* __restrict__ eids, int* __restrict__ bcnt,
                                 const float* __restrict__ W1,
                                 unsigned short* __restrict__ W1fh, unsigned short* __restrict__ W1fl,
                                 const float* __restrict__ Wa,
                                 unsigned short* __restrict__ Wafh, unsigned short* __restrict__ Wafl,
                                 int B) {
    const int tid = threadIdx.x;
    const int bx = blockIdx.x;
    if (bx < HB) {
        __shared__ int h[NE];
        if (tid < NE) h[tid] = 0;
        __syncthreads();
        const int per = B / HB, base = bx * per;
        for (int i = tid; i < per; i += blockDim.x) {
            const int e = expert_id(nq[base + i], lq[base + i], mq[base + i]);
            eids[base + i] = e;
            atomicAdd(&h[e], 1);
        }
        __syncthreads();
        if (tid < NE) bcnt[bx * NE + tid] = h[tid];
    } else if (bx == HB) {
        // W1 (128,64) -> hi/lo planes in B-frag order (rec=((c*4+nt)*4+qd)*16+l16)
        for (int i = tid; i < 8192; i += blockDim.x) {
            const int j = i & 7, s = (i >> 3) & 15, q = (i >> 7) & 3;
            const int nt = (i >> 9) & 3, c = i >> 11;
            const int k = c * 32 + q * 8 + j, n = nt * 16 + s;
            const float w = W1[k * 64 + n];
            const unsigned int hb = f2b(w);
            W1fh[i] = (unsigned short)hb;
            W1fl[i] = (unsigned short)f2b(w - b2f(hb));
        }
    } else {
        // Wa[e] (64,32) -> hi/lo planes (rec=((c2*2+nt2)*4+qd)*16+l16)
        const int e = bx - HB - 1;
        for (int i = tid; i < 2048; i += blockDim.x) {
            const int j = i & 7, s = (i >> 3) & 15, q = (i >> 7) & 3;
            const int nt2 = (i >> 9) & 1, c2 = (i >> 10) & 1;
            const int d = c2 * 32 + q * 8 + j, hh = nt2 * 16 + s;
            const float w = Wa[e * 2048 + d * 32 + hh];
            const unsigned int hb = f2b(w);
            Wafh[e * 2048 + i] = (unsigned short)hb;
            Wafl[e * 2048 + i] = (unsigned short)f2b(w - b2f(hb));
        }
    }
}

// ---- K2: scatter; derives scan + own bases from count table; publishes etot ----
__global__ void scatter_kernel(const int* __restrict__ eids, const int* __restrict__ bcnt,
                               int* __restrict__ etot, int* __restrict__ perm, int B) {
    __shared__ int sh[HB * NE];
    __shared__ int esrt[NE], bb[NE], lcnt[NE], tot[NE];
    const int tid = threadIdx.x;
    for (int i = tid; i < HB * NE; i += blockDim.x) sh[i] = bcnt[i];
    if (tid < NE) lcnt[tid] = 0;
    __syncthreads();
    if (tid < NE) {
        int pre = 0, t = 0;
        for (int b = 0; b < HB; ++b) {
            const int v = sh[b * NE + tid];
            if (b < (int)blockIdx.x) pre += v;
            t += v;
        }
        tot[tid] = t;
        bb[tid] = pre;
        if (blockIdx.x == 0) etot[tid] = t;     // publish for wfc
    }
    __syncthreads();
    if (tid == 0) {
        int es = 0;
        for (int e = 0; e < NE; ++e) { esrt[e] = es; es += tot[e]; }
    }
    __syncthreads();
    const int per = B / gridDim.x;
    const int blk = blockIdx.x * per;
    for (int i = tid; i < per; i += blockDim.x) {
        const int idx = blk + i;
        const int e = eids[idx];
        const int r = atomicAdd(&lcnt[e], 1);
        perm[esrt[e] + bb[e] + r] = idx;
    }
}

// ---- K3: fused MLP; MFMA GEMMs; zero barriers (all LDS wave-private rows) ----
__global__ __launch_bounds__(THREADS, 3) void wfc_kernel(
    const float* __restrict__ x, const int* __restrict__ perm,
    const int* __restrict__ etot,
    const float* __restrict__ W0, const float* __restrict__ b0,
    const bf16x8* __restrict__ W1fh, const bf16x8* __restrict__ W1fl,
    const float* __restrict__ b1,
    const bf16x8* __restrict__ Wafh, const bf16x8* __restrict__ Wafl,
    const float* __restrict__ ba,
    const float* __restrict__ Wb, const float* __restrict__ bb,
    float* __restrict__ out)
{
    __shared__ unsigned int sbuf[256 * SR];  // 36,864 B; row = sample (wave-private)

    // derive (eid, start, cnt) from etot: uniform scalar 30-iter scan
    int eid = -1, start = 0, cnt = 0;
    {
        int cum = 0, es = 0;
#pragma unroll 1
        for (int e = 0; e < NE; ++e) {
            const int t = etot[e];
            const int nb = (t + THREADS - 1) >> 8;
            if ((int)blockIdx.x < cum + nb) {
                const int seg = blockIdx.x - cum;
                eid = e; start = es + seg * THREADS; cnt = min(THREADS, t - seg * THREADS);
                break;
            }
            cum += nb; es += t;
        }
    }
    if (eid < 0) return;
    eid = __builtin_amdgcn_readfirstlane(eid);

    const int tid = threadIdx.x;
    const bool valid = tid < cnt;
    const int idx = perm[start + (valid ? tid : 0)];

    const int lane = tid & 63;
    const int wv   = tid >> 6;
    const int qd   = lane >> 4;
    const int l16  = lane & 15;

    const float x0 = x[idx * 3 + 0];
    const float x1 = x[idx * 3 + 1];
    const float x2 = x[idx * 3 + 2];

    // ---- layer 2 accumulators, init b1 (C layout: col = l16) ----
    f32x4 acc[4][4];
#pragma unroll
    for (int nt = 0; nt < 4; ++nt) {
        const float bv = b1[nt * 16 + l16];
#pragma unroll
        for (int mt = 0; mt < 4; ++mt) {
            f32x4 c; c[0] = bv; c[1] = bv; c[2] = bv; c[3] = bv;
            acc[mt][nt] = c;
        }
    }

    // ---- layer-2 GEMM: 4 K-chunks of 32; [sample][k] staging, b128 both ways ----
    uint4* srow = (uint4*)(sbuf + tid * SR);             // own row, 16B-aligned
    for (int c = 0; c < 4; ++c) {
#pragma unroll
        for (int g4 = 0; g4 < 8; ++g4) {
            uint4 w;
#pragma unroll
            for (int i = 0; i < 4; ++i) {
                const int k = c * 32 + g4 * 4 + i;
                const float pre = fmaf(x0, W0[k], fmaf(x1, W0[128 + k], fmaf(x2, W0[256 + k], b0[k])));
                ((unsigned int*)&w)[i] = packsplit(fast_tanh(pre));
            }
            srow[g4] = w;                                // ds_write_b128
        }

        bf16x8 Bhi[4], Blo[4];
#pragma unroll
        for (int nt = 0; nt < 4; ++nt) {
            const int rec = (c * 4 + nt) * 64 + qd * 16 + l16;
            Bhi[nt] = W1fh[rec];
            Blo[nt] = W1fl[rec];
        }
#pragma unroll
        for (int mt = 0; mt < 4; ++mt) {
            const int mrow = wv * 64 + mt * 16 + l16;
            const uint4* ar = (const uint4*)(sbuf + mrow * SR + qd * 8);
            uint4 u0 = ar[0], u1 = ar[1];                // 2x ds_read_b128
            unsigned int a[8] = {u0.x, u0.y, u0.z, u0.w, u1.x, u1.y, u1.z, u1.w};
            bf16x8 Ahi, Alo;
            unpack8(a, Ahi, Alo);
#pragma unroll
            for (int nt = 0; nt < 4; ++nt) {
                acc[mt][nt] = __builtin_amdgcn_mfma_f32_16x16x32_bf16(Ahi, Bhi[nt], acc[mt][nt], 0, 0, 0);
                acc[mt][nt] = __builtin_amdgcn_mfma_f32_16x16x32_bf16(Ahi, Blo[nt], acc[mt][nt], 0, 0, 0);
                acc[mt][nt] = __builtin_amdgcn_mfma_f32_16x16x32_bf16(Alo, Bhi[nt], acc[mt][nt], 0, 0, 0);
            }
        }
    }

    // ---- expert-A accumulators, init ba ----
    f32x4 acc2[4][2];
#pragma unroll
    for (int nt2 = 0; nt2 < 2; ++nt2) {
        const float bv = ba[(eid << 5) + nt2 * 16 + l16];
#pragma unroll
        for (int mt = 0; mt < 4; ++mt) {
            f32x4 c; c[0] = bv; c[1] = bv; c[2] = bv; c[3] = bv;
            acc2[mt][nt2] = c;
        }
    }

    // ---- expert-A GEMM: h2 restaged [sample][d-local]; 2 K-chunks ----
    const bf16x8* __restrict__ waeh = Wafh + (eid << 8);
    const bf16x8* __restrict__ wael = Wafl + (eid << 8);
    for (int c2 = 0; c2 < 2; ++c2) {
#pragma unroll
        for (int mt = 0; mt < 4; ++mt) {
#pragma unroll
            for (int ntl = 0; ntl < 2; ++ntl) {
#pragma unroll
                for (int r = 0; r < 4; ++r) {
                    const float h2 = fast_tanh(acc[mt][c2 * 2 + ntl][r]);
                    const int row = wv * 64 + mt * 16 + qd * 4 + r;   // sample (own wave)
                    sbuf[row * SR + ntl * 16 + l16] = packsplit(h2);  // col = d local
                }
            }
        }

        bf16x8 B2hi[2], B2lo[2];
#pragma unroll
        for (int nt2 = 0; nt2 < 2; ++nt2) {
            const int rec = (c2 * 2 + nt2) * 64 + qd * 16 + l16;
            B2hi[nt2] = waeh[rec];
            B2lo[nt2] = wael[rec];
        }
#pragma unroll
        for (int mt = 0; mt < 4; ++mt) {
            const int mrow = wv * 64 + mt * 16 + l16;
            const uint4* ar = (const uint4*)(sbuf + mrow * SR + qd * 8);
            uint4 u0 = ar[0], u1 = ar[1];
            unsigned int a[8] = {u0.x, u0.y, u0.z, u0.w, u1.x, u1.y, u1.z, u1.w};
            bf16x8 Ahi, Alo;
            unpack8(a, Ahi, Alo);
#pragma unroll
            for (int nt2 = 0; nt2 < 2; ++nt2) {
                acc2[mt][nt2] = __builtin_amdgcn_mfma_f32_16x16x32_bf16(Ahi, B2hi[nt2], acc2[mt][nt2], 0, 0, 0);
                acc2[mt][nt2] = __builtin_amdgcn_mfma_f32_16x16x32_bf16(Ahi, B2lo[nt2], acc2[mt][nt2], 0, 0, 0);
                acc2[mt][nt2] = __builtin_amdgcn_mfma_f32_16x16x32_bf16(Alo, B2hi[nt2], acc2[mt][nt2], 0, 0, 0);
            }
        }
    }

    // ---- g = tanh(acc2) staged [sample][h] in the SAME stride-SR rows ----
    // (row = sample = wave-private -> no cross-wave aliasing -> no barrier)
    float* g2 = (float*)sbuf;
#pragma unroll
    for (int mt = 0; mt < 4; ++mt) {
#pragma unroll
        for (int nt2 = 0; nt2 < 2; ++nt2) {
#pragma unroll
            for (int r = 0; r < 4; ++r) {
                const int row = wv * 64 + mt * 16 + qd * 4 + r;
                g2[row * SR + nt2 * 16 + l16] = fast_tanh(acc2[mt][nt2][r]);
            }
        }
    }

    float gv[32];
    {
        const float4* grow = (const float4*)(g2 + tid * SR);
#pragma unroll
        for (int i = 0; i < 8; ++i) {
            float4 v = grow[i];
            gv[4 * i + 0] = v.x; gv[4 * i + 1] = v.y;
            gv[4 * i + 2] = v.z; gv[4 * i + 3] = v.w;
        }
    }

    const float* __restrict__ wbe = Wb + (eid << 6);
    float p0 = bb[2 * eid], p1 = bb[2 * eid + 1];
#pragma unroll
    for (int h = 0; h < 32; ++h) {
        p0 = fmaf(gv[h], wbe[2 * h + 0], p0);
        p1 = fmaf(gv[h], wbe[2 * h + 1], p1);
    }

    const float s = fmaf(p0, p0, fmaf(p1, p1, 1e-6f));
    const float inv = 1.0f / sqrtf(s);
    if (valid) {
        float2 o; o.x = p0 * inv; o.y = p1 * inv;
        ((float2*)out)[idx] = o;
    }
}

extern "C" void kernel_launch(void* const* d_in, const int* in_sizes, int n_in,
                              void* d_out, int out_size, void* d_ws, size_t ws_size,
                              hipStream_t stream) {
    const float* x  = (const float*)d_in[0];
    const int*   n  = (const int*)d_in[1];
    const int*   l  = (const int*)d_in[2];
    const int*   m  = (const int*)d_in[3];
    const float* W0 = (const float*)d_in[4];
    const float* b0 = (const float*)d_in[5];
    const float* W1 = (const float*)d_in[6];
    const float* b1 = (const float*)d_in[7];
    const float* Wa = (const float*)d_in[8];
    const float* ba = (const float*)d_in[9];
    const float* Wb = (const float*)d_in[10];
    const float* bb = (const float*)d_in[11];
    float* out = (float*)d_out;

    const int B = in_sizes[1];   // 262144

    // workspace layout (all segments 16B aligned)
    int*            perm = (int*)d_ws;                       // B
    int*            eids = perm + B;                         // B
    int*            bcnt = eids + B;                         // HB*NE = 3840
    int*            etot = bcnt + HB * NE;                   // 32
    unsigned short* W1fh = (unsigned short*)(etot + 32);     // 8192 u16
    unsigned short* W1fl = W1fh + 8192;                      // 8192 u16
    unsigned short* Wafh = W1fl + 8192;                      // 30*2048 u16
    unsigned short* Wafl = Wafh + NE * 2048;                 // 30*2048 u16

    hist_pack_kernel<<<HB + 1 + NE, 256, 0, stream>>>(
        n, l, m, eids, bcnt, W1, W1fh, W1fl, Wa, Wafh, Wafl, B);
    scatter_kernel<<<HB, 256, 0, stream>>>(eids, bcnt, etot, perm, B);
    wfc_kernel<<<MAXBLK, THREADS, 0, stream>>>(
        x, perm, etot, W0, b0,
        (const bf16x8*)W1fh, (const bf16x8*)W1fl, b1,
        (const bf16x8*)Wafh, (const bf16x8*)Wafl, ba, Wb, bb, out);
}